// Round 1
// baseline (244.441 us; speedup 1.0000x reference)
//
#include <hip/hip_runtime.h>
#include <stdint.h>
#include <math.h>

typedef unsigned short u16;
typedef __bf16 bf16x8 __attribute__((ext_vector_type(8)));
typedef float f32x4 __attribute__((ext_vector_type(4)));

enum { M_QKV = 0, M_SCORE = 1, M_PV = 2 };

// fp32 -> bf16 round-to-nearest-even, bit-level
__device__ __forceinline__ u16 f2bf(float f) {
    union { float f; unsigned int u; } a; a.f = f;
    unsigned int u = a.u;
    u += 0x7FFFu + ((u >> 16) & 1u);
    return (u16)(u >> 16);
}

__device__ __forceinline__ void async_load16(const void* g, void* l) {
    __builtin_amdgcn_global_load_lds(
        (const __attribute__((address_space(1))) void*)g,
        (__attribute__((address_space(3))) void*)l,
        16, 0, 0);
}

// ---------------------------------------------------------------------------
// Shared GEMM core (bf16 in, fp32 acc), TBM x 128 tile, KB=64/iter, 4 waves
// 2x2. LDS granule (row,g) at slot g^(row&7); staging permutes the *global*
// granule per lane (R3/R5-verified family: 0 bank conflicts).
// ---------------------------------------------------------------------------
template<int MODE, int TBM>
__device__ __forceinline__ void gemm_core(
    const u16* __restrict__ A, const u16* __restrict__ Bt,
    void* __restrict__ Cv, float* __restrict__ rowsum,
    int bm, int bn, int bz, int M, int N, int K, float kfac,
    u16* As, u16* Bs)
{
    constexpr int KB  = 64;
    constexpr int NI  = TBM / 32;        // m-frags per wave
    constexpr int ACH = TBM / 32;        // A staging chunks per wave
    constexpr int BCH = 4;               // B staging chunks per wave

    const int tid  = threadIdx.x;
    const int lane = tid & 63;
    const int wv   = tid >> 6;
    const int wm   = wv >> 1;
    const int wn   = wv & 1;

    f32x4 acc[NI][4] = {};

    const int rowA0 = bm * TBM, rowB0 = bn * 128;
    const int lrow  = lane >> 3;
    const int lslot = lane & 7;
    const int sg    = (lslot ^ lrow) * 8;

    int kEnd = K;
    if (MODE == M_PV) { int ke = (bm + 1) * TBM; kEnd = ke < K ? ke : K; }

    const int lm   = lane & 15;
    const int quad = lane >> 4;
    const int rx   = lm & 7;

    for (int k0 = 0; k0 < kEnd; k0 += KB) {
        #pragma unroll
        for (int c = 0; c < ACH; ++c) {
            const int cc  = wv * ACH + c;
            const int row = cc * 8 + lrow;
            async_load16(&A[(size_t)(rowA0 + row) * K + k0 + sg], &As[cc * 512 + lane * 8]);
        }
        #pragma unroll
        for (int c = 0; c < BCH; ++c) {
            const int cc  = wv * BCH + c;
            const int row = cc * 8 + lrow;
            async_load16(&Bt[(size_t)(rowB0 + row) * K + k0 + sg], &Bs[cc * 512 + lane * 8]);
        }
        __syncthreads();

        #pragma unroll
        for (int h = 0; h < 2; ++h) {
            const int sl = (((h * 4 + quad) ^ rx) * 8);
            bf16x8 af[NI], bfr[4];
            #pragma unroll
            for (int i = 0; i < NI; ++i)
                af[i] = *reinterpret_cast<const bf16x8*>(
                    &As[(wm * (TBM / 2) + i * 16 + lm) * KB + sl]);
            #pragma unroll
            for (int j = 0; j < 4; ++j)
                bfr[j] = *reinterpret_cast<const bf16x8*>(
                    &Bs[(wn * 64 + j * 16 + lm) * KB + sl]);
            #pragma unroll
            for (int i = 0; i < NI; ++i)
                #pragma unroll
                for (int j = 0; j < 4; ++j)
                    acc[i][j] = __builtin_amdgcn_mfma_f32_16x16x32_bf16(af[i], bfr[j], acc[i][j], 0, 0, 0);
        }
        __syncthreads();
    }

    // Epilogue. C/D layout (m89-verified): col = lane&15, row = quad*4 + reg.
    if (MODE == M_QKV) {
        u16* C = (u16*)Cv + (size_t)(bn >> 3) * ((size_t)M * 1024);  // 0-7:Q,8-15:K,16-23:V
        #pragma unroll
        for (int i = 0; i < NI; ++i)
            #pragma unroll
            for (int j = 0; j < 4; ++j) {
                const int r0 = rowA0 + wm * (TBM / 2) + i * 16 + quad * 4;
                const int c0 = (rowB0 + wn * 64 + j * 16 + lm) & 1023;
                #pragma unroll
                for (int g = 0; g < 4; ++g)
                    C[(size_t)(r0 + g) * 1024 + c0] = f2bf(acc[i][j][g]);
            }
    } else if (MODE == M_SCORE) {
        u16* E = (u16*)Cv + (size_t)bz * ((size_t)M * N);
        float rs[NI][4];
        #pragma unroll
        for (int i = 0; i < NI; ++i)
            #pragma unroll
            for (int g = 0; g < 4; ++g) rs[i][g] = 0.f;
        #pragma unroll
        for (int i = 0; i < NI; ++i)
            #pragma unroll
            for (int j = 0; j < 4; ++j) {
                const int r0 = rowA0 + wm * (TBM / 2) + i * 16 + quad * 4;
                const int c  = rowB0 + wn * 64 + j * 16 + lm;
                #pragma unroll
                for (int g = 0; g < 4; ++g) {
                    const int r = r0 + g;
                    float e = (c <= r) ? exp2f(acc[i][j][g] * kfac) : 0.f;
                    E[(size_t)r * N + c] = f2bf(e);
                    rs[i][g] += e;
                }
            }
        #pragma unroll
        for (int i = 0; i < NI; ++i)
            #pragma unroll
            for (int g = 0; g < 4; ++g) {
                float v = rs[i][g];
                v += __shfl_xor(v, 1); v += __shfl_xor(v, 2);
                v += __shfl_xor(v, 4); v += __shfl_xor(v, 8);
                rs[i][g] = v;
            }
        if (lm == 0) {
            #pragma unroll
            for (int i = 0; i < NI; ++i)
                #pragma unroll
                for (int g = 0; g < 4; ++g) {
                    const int r = rowA0 + wm * (TBM / 2) + i * 16 + quad * 4 + g;
                    atomicAdd(&rowsum[(size_t)bz * M + r], rs[i][g]);
                }
        }
    } else {  // M_PV
        float* C = (float*)Cv + (size_t)bz * ((size_t)M * N);
        #pragma unroll
        for (int i = 0; i < NI; ++i) {
            const int r0 = rowA0 + wm * (TBM / 2) + i * 16 + quad * 4;
            float inv[4];
            #pragma unroll
            for (int g = 0; g < 4; ++g)
                inv[g] = 1.f / rowsum[(size_t)bz * M + r0 + g];
            #pragma unroll
            for (int j = 0; j < 4; ++j) {
                const int c0 = rowB0 + wn * 64 + j * 16 + lm;
                #pragma unroll
                for (int g = 0; g < 4; ++g)
                    C[(size_t)(r0 + g) * N + c0] = acc[i][j][g] * inv[g];
            }
        }
    }
}

// QKV: 128x128 tiles, row-major Q|K|V out
__global__ __launch_bounds__(256)
void k_qkv(const u16* __restrict__ Xb, const u16* __restrict__ Wt,
           u16* __restrict__ Q, int M, int N, int K)
{
    __shared__ __attribute__((aligned(16))) u16 As[128 * 64];
    __shared__ __attribute__((aligned(16))) u16 Bs[128 * 64];
    gemm_core<M_QKV, 128>(Xb, Wt, Q, nullptr, blockIdx.y, blockIdx.x, 0,
                          M, N, K, 0.f, As, Bs);
}

// S (tri 128x128 blocks) + V-transpose (trailing blocks fill the tail).
// Blocks [0, nTri): E = exp2(kfac * Q K^T) causal + rowsum.
// Blocks [nTri, nTri+2048): 32x32 transpose tiles of V -> Vt[b][c][t].
__global__ __launch_bounds__(256)
void k_score_vt(const u16* __restrict__ Q, const u16* __restrict__ Kb,
                u16* __restrict__ E, float* __restrict__ rowsum,
                const u16* __restrict__ Vb, u16* __restrict__ Vt,
                int T, int D, float kfac, int nTri)
{
    __shared__ __attribute__((aligned(16))) u16 As[128 * 64];
    __shared__ __attribute__((aligned(16))) u16 Bs[128 * 64];
    __shared__ u16 tt[32][33];
    const int bz = blockIdx.z;

    if ((int)blockIdx.x < nTri) {
        // standard triangular decode: idx = bm*(bm+1)/2 + bn, bn <= bm
        const int idx = blockIdx.x;
        int bm = (int)((sqrtf(8.f * (float)idx + 1.f) - 1.f) * 0.5f);
        while (bm * (bm + 1) / 2 > idx) --bm;
        while ((bm + 1) * (bm + 2) / 2 <= idx) ++bm;
        const int bn = idx - bm * (bm + 1) / 2;
        gemm_core<M_SCORE, 128>(Q + (size_t)bz * T * D, Kb + (size_t)bz * T * D,
                                E, rowsum, bm, bn, bz, T, T, D, kfac, As, Bs);
    } else {
        const int t  = blockIdx.x - nTri;
        const int cx = t & 31;          // D/32 tiles
        const int cy = t >> 5;          // T/32 tiles
        const u16* V = Vb + (size_t)bz * T * D;
        u16*      Vo = Vt + (size_t)bz * D * T;
        const int c0 = cx * 32, r0 = cy * 32;
        const int tx = threadIdx.x & 31, ty = threadIdx.x >> 5;
        #pragma unroll
        for (int s = 0; s < 32; s += 8)
            tt[ty + s][tx] = V[(size_t)(r0 + ty + s) * D + c0 + tx];
        __syncthreads();
        #pragma unroll
        for (int s = 0; s < 32; s += 8)
            Vo[(size_t)(c0 + ty + s) * T + r0 + tx] = tt[tx][ty + s];
    }
}

// PV: 128x128 tiles, heavy rows (large bm) dispatched FIRST (LPT scheduling)
__global__ __launch_bounds__(256)
void k_pv(const u16* __restrict__ E, const u16* __restrict__ Vt,
          float* __restrict__ out, const float* __restrict__ rowsum,
          int T, int D)
{
    __shared__ __attribute__((aligned(16))) u16 As[128 * 64];
    __shared__ __attribute__((aligned(16))) u16 Bs[128 * 64];
    const int bz = blockIdx.z;
    const int bm = (gridDim.y - 1) - blockIdx.y;   // heavy-first
    gemm_core<M_PV, 128>(E + (size_t)bz * T * T, Vt + (size_t)bz * D * T,
                         out, (float*)rowsum, bm, blockIdx.x, bz,
                         T, D, T, 0.f, As, Bs);
}

// prep: cast_x (blocks [0,nCX)) + W transpose-cast ([nCX,nCX+nW)) + RS zero
__global__ __launch_bounds__(256)
void k_prep(const float* __restrict__ x,
            const float* __restrict__ W0, const float* __restrict__ W1,
            const float* __restrict__ W2,
            u16* __restrict__ Xb, u16* __restrict__ Wt, float* __restrict__ RS,
            int D, int nCX, int nW)
{
    const int bx = blockIdx.x;
    if (bx < nCX) {
        long long i = ((long long)bx * 256 + threadIdx.x) * 8;
        const float4 a = *(const float4*)(x + i);
        const float4 b = *(const float4*)(x + i + 4);
        union { u16 u[8]; float4 v; } r;
        r.u[0] = f2bf(a.x); r.u[1] = f2bf(a.y); r.u[2] = f2bf(a.z); r.u[3] = f2bf(a.w);
        r.u[4] = f2bf(b.x); r.u[5] = f2bf(b.y); r.u[6] = f2bf(b.z); r.u[7] = f2bf(b.w);
        *(float4*)(Xb + i) = r.v;
    } else if (bx < nCX + nW) {
        __shared__ u16 t[32][33];
        const int w  = bx - nCX;
        const int z  = w >> 10;                 // 1024 tiles per matrix (32x32)
        const int rm = w & 1023;
        const float* W = z == 0 ? W0 : (z == 1 ? W1 : W2);
        u16* dst = Wt + (size_t)z * D * D;
        const int c0 = (rm & 31) * 32, r0 = (rm >> 5) * 32;
        const int tx = threadIdx.x & 31, ty = threadIdx.x >> 5;
        #pragma unroll
        for (int s = 0; s < 32; s += 8)
            t[ty + s][tx] = f2bf(W[(size_t)(r0 + ty + s) * D + c0 + tx]);
        __syncthreads();
        #pragma unroll
        for (int s = 0; s < 32; s += 8)
            dst[(size_t)(c0 + ty + s) * D + r0 + tx] = t[tx][ty + s];
    } else {
        const int t = bx - nCX - nW;
        ((float4*)RS)[t * 256 + threadIdx.x] = float4{0.f, 0.f, 0.f, 0.f};
    }
}

extern "C" void kernel_launch(void* const* d_in, const int* in_sizes, int n_in,
                              void* d_out, int out_size, void* d_ws, size_t ws_size,
                              hipStream_t stream)
{
    const int B = 4, T = 2048, D = 1024;
    const float* x  = (const float*)d_in[0];
    const float* Wq = (const float*)d_in[1];
    const float* Wk = (const float*)d_in[2];
    const float* Wv = (const float*)d_in[3];
    float* out = (float*)d_out;

    const size_t nX = (size_t)B * T * D;
    u16* Xb = (u16*)d_ws;                          // [B*T, D] bf16
    u16* Wt = Xb + nX;                             // 3 x [D, D] bf16 transposed
    u16* Q  = Wt + 3 * (size_t)D * D;              // [B*T, D]  (Q,K,V contiguous)
    u16* Kb = Q + nX;
    u16* Vb = Kb + nX;
    u16* Vt = Vb + nX;                             // [B][D][T]
    char* rest = (char*)(Vt + nX);
    const size_t fixed   = (size_t)((char*)rest - (char*)d_ws);
    const size_t perb_E  = (size_t)T * T * 2;
    const size_t perb_rs = (size_t)T * 4;
    const bool full = ws_size >= fixed + (size_t)B * (perb_E + perb_rs);
    const int nb = full ? B : 1;
    u16*   E  = (u16*)rest;
    float* RS = (float*)(E + nb * (size_t)T * T);

    const float kfac = 1.4426950408889634f / 32.0f;  // log2(e)/sqrt(d_out)
    const int nTri128 = 136;  // sum_{bm=0..15} (bm+1), 128x128 tri tiles
    const int nCX = (int)(nX / (8 * 256));           // 4096 cast blocks
    const int nW  = 3 * (D / 32) * (D / 32);         // 3072 W-transpose blocks
    const int nRS = (nb * T) / (4 * 256);            // RS-zero blocks (float4)

    if (full) {
        // 1. prep: x-cast + W-transpose-cast + RS zero, one dispatch
        k_prep<<<dim3(nCX + nW + nRS), 256, 0, stream>>>(
            x, Wq, Wk, Wv, Xb, Wt, RS, D, nCX, nW);
        // 2. merged QKV projection (128x128, KB=64: measured 805 TF / 64 us)
        k_qkv<<<dim3(3 * D / 128, (B * T) / 128), 256, 0, stream>>>(
            Xb, Wt, Q, B * T, 3 * D, D);
        // 3. S (136 tri blocks/batch) + V-transpose (2048 tail-fill blocks)
        k_score_vt<<<dim3(nTri128 + (D / 32) * (T / 32), 1, B), 256, 0, stream>>>(
            Q, Kb, E, RS, Vb, Vt, T, D, kfac, nTri128);
        // 4. PV, heavy-first
        k_pv<<<dim3(D / 128, T / 128, B), 256, 0, stream>>>(E, Vt, out, RS, T, D);
    } else {
        k_prep<<<dim3(nCX + nW + nRS), 256, 0, stream>>>(
            x, Wq, Wk, Wv, Xb, Wt, RS, D, nCX, nW);
        k_qkv<<<dim3(3 * D / 128, (B * T) / 128), 256, 0, stream>>>(
            Xb, Wt, Q, B * T, 3 * D, D);
        for (int b = 0; b < B; ++b) {
            const size_t ob = (size_t)b * T * D;
            if (b) hipMemsetAsync(RS, 0, (size_t)T * 4, stream);
            k_score_vt<<<dim3(nTri128 + (D / 32) * (T / 32), 1, 1), 256, 0, stream>>>(
                Q + ob, Kb + ob, E, RS, Vb + ob, Vt, T, D, kfac, nTri128);
            k_pv<<<dim3(D / 128, T / 128, 1), 256, 0, stream>>>(
                E, Vt, out + ob, RS, T, D);
        }
    }
}

// Round 2
// 244.378 us; speedup vs baseline: 1.0003x; 1.0003x over previous
//
#include <hip/hip_runtime.h>
#include <stdint.h>
#include <math.h>

typedef unsigned short u16;
typedef __bf16 bf16x8 __attribute__((ext_vector_type(8)));
typedef float f32x4 __attribute__((ext_vector_type(4)));

enum { M_QKV = 0, M_SCORE = 1, M_PV = 2 };

// fp32 -> bf16 round-to-nearest-even, bit-level
__device__ __forceinline__ u16 f2bf(float f) {
    union { float f; unsigned int u; } a; a.f = f;
    unsigned int u = a.u;
    u += 0x7FFFu + ((u >> 16) & 1u);
    return (u16)(u >> 16);
}

__device__ __forceinline__ void async_load16(const void* g, void* l) {
    __builtin_amdgcn_global_load_lds(
        (const __attribute__((address_space(1))) void*)g,
        (__attribute__((address_space(3))) void*)l,
        16, 0, 0);
}

// ---------------------------------------------------------------------------
// Shared GEMM core (bf16 in, fp32 acc), TBM x 128 tile, KB=64/iter, 4 waves
// 2x2. LDS granule (row,g) at slot g^(row&7); staging permutes the *global*
// granule per lane (R3/R5-verified family: 0 bank conflicts).
// ---------------------------------------------------------------------------
template<int MODE, int TBM>
__device__ __forceinline__ void gemm_core(
    const u16* __restrict__ A, const u16* __restrict__ Bt,
    void* __restrict__ Cv, float* __restrict__ rowsum,
    int bm, int bn, int bz, int M, int N, int K, float kfac,
    u16* As, u16* Bs)
{
    constexpr int KB  = 64;
    constexpr int NI  = TBM / 32;        // m-frags per wave
    constexpr int ACH = TBM / 32;        // A staging chunks per wave
    constexpr int BCH = 4;               // B staging chunks per wave

    const int tid  = threadIdx.x;
    const int lane = tid & 63;
    const int wv   = tid >> 6;
    const int wm   = wv >> 1;
    const int wn   = wv & 1;

    f32x4 acc[NI][4] = {};

    const int rowA0 = bm * TBM, rowB0 = bn * 128;
    const int lrow  = lane >> 3;
    const int lslot = lane & 7;
    const int sg    = (lslot ^ lrow) * 8;

    int kEnd = K;
    if (MODE == M_PV) { int ke = (bm + 1) * TBM; kEnd = ke < K ? ke : K; }

    const int lm   = lane & 15;
    const int quad = lane >> 4;
    const int rx   = lm & 7;

    for (int k0 = 0; k0 < kEnd; k0 += KB) {
        #pragma unroll
        for (int c = 0; c < ACH; ++c) {
            const int cc  = wv * ACH + c;
            const int row = cc * 8 + lrow;
            async_load16(&A[(size_t)(rowA0 + row) * K + k0 + sg], &As[cc * 512 + lane * 8]);
        }
        #pragma unroll
        for (int c = 0; c < BCH; ++c) {
            const int cc  = wv * BCH + c;
            const int row = cc * 8 + lrow;
            async_load16(&Bt[(size_t)(rowB0 + row) * K + k0 + sg], &Bs[cc * 512 + lane * 8]);
        }
        __syncthreads();

        #pragma unroll
        for (int h = 0; h < 2; ++h) {
            const int sl = (((h * 4 + quad) ^ rx) * 8);
            bf16x8 af[NI], bfr[4];
            #pragma unroll
            for (int i = 0; i < NI; ++i)
                af[i] = *reinterpret_cast<const bf16x8*>(
                    &As[(wm * (TBM / 2) + i * 16 + lm) * KB + sl]);
            #pragma unroll
            for (int j = 0; j < 4; ++j)
                bfr[j] = *reinterpret_cast<const bf16x8*>(
                    &Bs[(wn * 64 + j * 16 + lm) * KB + sl]);
            #pragma unroll
            for (int i = 0; i < NI; ++i)
                #pragma unroll
                for (int j = 0; j < 4; ++j)
                    acc[i][j] = __builtin_amdgcn_mfma_f32_16x16x32_bf16(af[i], bfr[j], acc[i][j], 0, 0, 0);
        }
        __syncthreads();
    }

    // Epilogue. C/D layout (m89-verified): col = lane&15, row = quad*4 + reg.
    if (MODE == M_QKV) {
        u16* C = (u16*)Cv + (size_t)(bn >> 3) * ((size_t)M * 1024);  // 0-7:Q,8-15:K,16-23:V
        #pragma unroll
        for (int i = 0; i < NI; ++i)
            #pragma unroll
            for (int j = 0; j < 4; ++j) {
                const int r0 = rowA0 + wm * (TBM / 2) + i * 16 + quad * 4;
                const int c0 = (rowB0 + wn * 64 + j * 16 + lm) & 1023;
                #pragma unroll
                for (int g = 0; g < 4; ++g)
                    C[(size_t)(r0 + g) * 1024 + c0] = f2bf(acc[i][j][g]);
            }
    } else if (MODE == M_SCORE) {
        u16* E = (u16*)Cv + (size_t)bz * ((size_t)M * N);
        float rs[NI][4];
        #pragma unroll
        for (int i = 0; i < NI; ++i)
            #pragma unroll
            for (int g = 0; g < 4; ++g) rs[i][g] = 0.f;
        #pragma unroll
        for (int i = 0; i < NI; ++i)
            #pragma unroll
            for (int j = 0; j < 4; ++j) {
                const int r0 = rowA0 + wm * (TBM / 2) + i * 16 + quad * 4;
                const int c  = rowB0 + wn * 64 + j * 16 + lm;
                #pragma unroll
                for (int g = 0; g < 4; ++g) {
                    const int r = r0 + g;
                    float e = (c <= r) ? exp2f(acc[i][j][g] * kfac) : 0.f;
                    E[(size_t)r * N + c] = f2bf(e);
                    rs[i][g] += e;
                }
            }
        #pragma unroll
        for (int i = 0; i < NI; ++i)
            #pragma unroll
            for (int g = 0; g < 4; ++g) {
                float v = rs[i][g];
                v += __shfl_xor(v, 1); v += __shfl_xor(v, 2);
                v += __shfl_xor(v, 4); v += __shfl_xor(v, 8);
                rs[i][g] = v;
            }
        if (lm == 0) {
            #pragma unroll
            for (int i = 0; i < NI; ++i)
                #pragma unroll
                for (int g = 0; g < 4; ++g) {
                    const int r = rowA0 + wm * (TBM / 2) + i * 16 + quad * 4 + g;
                    atomicAdd(&rowsum[(size_t)bz * M + r], rs[i][g]);
                }
        }
    } else {  // M_PV
        float* C = (float*)Cv + (size_t)bz * ((size_t)M * N);
        #pragma unroll
        for (int i = 0; i < NI; ++i) {
            const int r0 = rowA0 + wm * (TBM / 2) + i * 16 + quad * 4;
            float inv[4];
            #pragma unroll
            for (int g = 0; g < 4; ++g)
                inv[g] = 1.f / rowsum[(size_t)bz * M + r0 + g];
            #pragma unroll
            for (int j = 0; j < 4; ++j) {
                const int c0 = rowB0 + wn * 64 + j * 16 + lm;
                #pragma unroll
                for (int g = 0; g < 4; ++g)
                    C[(size_t)(r0 + g) * N + c0] = acc[i][j][g] * inv[g];
            }
        }
    }
}

// ---------------------------------------------------------------------------
// k_qkv2: counted-vmcnt triple-buffered GEMM (T4). 128x256 tile, 8 waves
// (2M x 4N), wave tile 64x64, KB=64. 3 LDS buffers of 48KB (A 16KB + B 32KB).
// Each iter: issue stage(t+2) -> compute(t) -> s_waitcnt vmcnt(6) (own loads
// for t+1 retired; t+2's 6 stay in flight) -> raw s_barrier. Loads are never
// drained to 0 in the main loop. Swizzle family identical to gemm_core
// (verified 0-conflict).
// ---------------------------------------------------------------------------
__global__ __launch_bounds__(512, 2)
void k_qkv2(const u16* __restrict__ Xb, const u16* __restrict__ Wt,
            u16* __restrict__ Q, int M, int N, int K)
{
    extern __shared__ __attribute__((aligned(16))) u16 S[];
    const int tid  = threadIdx.x;
    const int lane = tid & 63;
    const int wv   = tid >> 6;           // 0..7
    const int wm   = wv >> 2;            // 0..1  (M half)
    const int wn   = wv & 3;             // 0..3  (N quarter)
    const int bn   = blockIdx.x;         // N/256
    const int bm   = blockIdx.y;         // M/128
    const int rowA0 = bm * 128, rowB0 = bn * 256;

    const int lrow  = lane >> 3;
    const int lslot = lane & 7;
    const int sg    = (lslot ^ lrow) * 8;
    const int lm    = lane & 15;
    const int quad  = lane >> 4;
    const int rx    = lm & 7;

    f32x4 acc[4][4] = {};

    const int nt = K >> 6;               // K/64 tiles (=16)

    // stage tile t into buffer b: A 128x64 (2 chunks/wave), B 256x64 (4/wave)
    auto stage = [&](int t, int b) {
        u16* As = S + b * 24576;
        u16* Bs = As + 8192;
        const int k0 = t << 6;
        #pragma unroll
        for (int c = 0; c < 2; ++c) {
            const int cc  = wv * 2 + c;
            const int row = cc * 8 + lrow;
            async_load16(&Xb[(size_t)(rowA0 + row) * K + k0 + sg], &As[cc * 512 + lane * 8]);
        }
        #pragma unroll
        for (int c = 0; c < 4; ++c) {
            const int cc  = wv * 4 + c;
            const int row = cc * 8 + lrow;
            async_load16(&Wt[(size_t)(rowB0 + row) * K + k0 + sg], &Bs[cc * 512 + lane * 8]);
        }
    };

    auto compute = [&](int b) {
        const u16* As = S + b * 24576;
        const u16* Bs = As + 8192;
        #pragma unroll
        for (int h = 0; h < 2; ++h) {
            const int sl = (((h * 4 + quad) ^ rx) * 8);
            bf16x8 af[4], bfr[4];
            #pragma unroll
            for (int i = 0; i < 4; ++i)
                af[i] = *reinterpret_cast<const bf16x8*>(
                    &As[(wm * 64 + i * 16 + lm) * 64 + sl]);
            #pragma unroll
            for (int j = 0; j < 4; ++j)
                bfr[j] = *reinterpret_cast<const bf16x8*>(
                    &Bs[(wn * 64 + j * 16 + lm) * 64 + sl]);
            #pragma unroll
            for (int i = 0; i < 4; ++i)
                #pragma unroll
                for (int j = 0; j < 4; ++j)
                    acc[i][j] = __builtin_amdgcn_mfma_f32_16x16x32_bf16(af[i], bfr[j], acc[i][j], 0, 0, 0);
        }
    };

    // prologue: tiles 0,1 in flight; wait own 6 of tile 0 (6 of tile 1 fly)
    stage(0, 0);
    stage(1, 1);
    asm volatile("s_waitcnt vmcnt(6)" ::: "memory");
    __builtin_amdgcn_s_barrier();

    int cb = 0;
    #pragma unroll 1
    for (int t = 0; t < nt - 2; ++t) {
        int sb = cb + 2; if (sb >= 3) sb -= 3;
        stage(t + 2, sb);
        compute(cb);
        asm volatile("s_waitcnt vmcnt(6)" ::: "memory");  // t+1 landed, t+2 flying
        __builtin_amdgcn_s_barrier();
        if (++cb == 3) cb = 0;
    }
    // t = nt-2: nothing to stage; drain so last tile is resident
    compute(cb);
    asm volatile("s_waitcnt vmcnt(0)" ::: "memory");
    __builtin_amdgcn_s_barrier();
    if (++cb == 3) cb = 0;
    // t = nt-1
    compute(cb);

    // epilogue: C/D layout col=lane&15, row=quad*4+g (m89-verified)
    u16* C = Q + (size_t)(bn >> 2) * ((size_t)M * 1024);   // which of Q/K/V
    const int cbase = (rowB0 & 1023) + wn * 64;
    #pragma unroll
    for (int i = 0; i < 4; ++i)
        #pragma unroll
        for (int j = 0; j < 4; ++j) {
            const int r0 = rowA0 + wm * 64 + i * 16 + quad * 4;
            const int c0 = cbase + j * 16 + lm;
            #pragma unroll
            for (int g = 0; g < 4; ++g)
                C[(size_t)(r0 + g) * 1024 + c0] = f2bf(acc[i][j][g]);
        }
}

// S (tri 128x128 blocks) + V-transpose (trailing blocks fill the tail).
// Blocks [0, nTri): E = exp2(kfac * Q K^T) causal + rowsum.
// Blocks [nTri, nTri+2048): 32x32 transpose tiles of V -> Vt[b][c][t].
__global__ __launch_bounds__(256)
void k_score_vt(const u16* __restrict__ Q, const u16* __restrict__ Kb,
                u16* __restrict__ E, float* __restrict__ rowsum,
                const u16* __restrict__ Vb, u16* __restrict__ Vt,
                int T, int D, float kfac, int nTri)
{
    __shared__ __attribute__((aligned(16))) u16 As[128 * 64];
    __shared__ __attribute__((aligned(16))) u16 Bs[128 * 64];
    __shared__ u16 tt[32][33];
    const int bz = blockIdx.z;

    if ((int)blockIdx.x < nTri) {
        // standard triangular decode: idx = bm*(bm+1)/2 + bn, bn <= bm
        const int idx = blockIdx.x;
        int bm = (int)((sqrtf(8.f * (float)idx + 1.f) - 1.f) * 0.5f);
        while (bm * (bm + 1) / 2 > idx) --bm;
        while ((bm + 1) * (bm + 2) / 2 <= idx) ++bm;
        const int bn = idx - bm * (bm + 1) / 2;
        gemm_core<M_SCORE, 128>(Q + (size_t)bz * T * D, Kb + (size_t)bz * T * D,
                                E, rowsum, bm, bn, bz, T, T, D, kfac, As, Bs);
    } else {
        const int t  = blockIdx.x - nTri;
        const int cx = t & 31;          // D/32 tiles
        const int cy = t >> 5;          // T/32 tiles
        const u16* V = Vb + (size_t)bz * T * D;
        u16*      Vo = Vt + (size_t)bz * D * T;
        const int c0 = cx * 32, r0 = cy * 32;
        const int tx = threadIdx.x & 31, ty = threadIdx.x >> 5;
        #pragma unroll
        for (int s = 0; s < 32; s += 8)
            tt[ty + s][tx] = V[(size_t)(r0 + ty + s) * D + c0 + tx];
        __syncthreads();
        #pragma unroll
        for (int s = 0; s < 32; s += 8)
            Vo[(size_t)(c0 + ty + s) * T + r0 + tx] = tt[tx][ty + s];
    }
}

// PV: 128x128 tiles, heavy rows (large bm) dispatched FIRST (LPT scheduling)
__global__ __launch_bounds__(256)
void k_pv(const u16* __restrict__ E, const u16* __restrict__ Vt,
          float* __restrict__ out, const float* __restrict__ rowsum,
          int T, int D)
{
    __shared__ __attribute__((aligned(16))) u16 As[128 * 64];
    __shared__ __attribute__((aligned(16))) u16 Bs[128 * 64];
    const int bz = blockIdx.z;
    const int bm = (gridDim.y - 1) - blockIdx.y;   // heavy-first
    gemm_core<M_PV, 128>(E + (size_t)bz * T * T, Vt + (size_t)bz * D * T,
                         out, (float*)rowsum, bm, blockIdx.x, bz,
                         T, D, T, 0.f, As, Bs);
}

// prep: cast_x (blocks [0,nCX)) + W transpose-cast ([nCX,nCX+nW)) + RS zero
__global__ __launch_bounds__(256)
void k_prep(const float* __restrict__ x,
            const float* __restrict__ W0, const float* __restrict__ W1,
            const float* __restrict__ W2,
            u16* __restrict__ Xb, u16* __restrict__ Wt, float* __restrict__ RS,
            int D, int nCX, int nW)
{
    const int bx = blockIdx.x;
    if (bx < nCX) {
        long long i = ((long long)bx * 256 + threadIdx.x) * 8;
        const float4 a = *(const float4*)(x + i);
        const float4 b = *(const float4*)(x + i + 4);
        union { u16 u[8]; float4 v; } r;
        r.u[0] = f2bf(a.x); r.u[1] = f2bf(a.y); r.u[2] = f2bf(a.z); r.u[3] = f2bf(a.w);
        r.u[4] = f2bf(b.x); r.u[5] = f2bf(b.y); r.u[6] = f2bf(b.z); r.u[7] = f2bf(b.w);
        *(float4*)(Xb + i) = r.v;
    } else if (bx < nCX + nW) {
        __shared__ u16 t[32][33];
        const int w  = bx - nCX;
        const int z  = w >> 10;                 // 1024 tiles per matrix (32x32)
        const int rm = w & 1023;
        const float* W = z == 0 ? W0 : (z == 1 ? W1 : W2);
        u16* dst = Wt + (size_t)z * D * D;
        const int c0 = (rm & 31) * 32, r0 = (rm >> 5) * 32;
        const int tx = threadIdx.x & 31, ty = threadIdx.x >> 5;
        #pragma unroll
        for (int s = 0; s < 32; s += 8)
            t[ty + s][tx] = f2bf(W[(size_t)(r0 + ty + s) * D + c0 + tx]);
        __syncthreads();
        #pragma unroll
        for (int s = 0; s < 32; s += 8)
            dst[(size_t)(c0 + ty + s) * D + r0 + tx] = t[tx][ty + s];
    } else {
        const int t = bx - nCX - nW;
        ((float4*)RS)[t * 256 + threadIdx.x] = float4{0.f, 0.f, 0.f, 0.f};
    }
}

extern "C" void kernel_launch(void* const* d_in, const int* in_sizes, int n_in,
                              void* d_out, int out_size, void* d_ws, size_t ws_size,
                              hipStream_t stream)
{
    const int B = 4, T = 2048, D = 1024;
    const float* x  = (const float*)d_in[0];
    const float* Wq = (const float*)d_in[1];
    const float* Wk = (const float*)d_in[2];
    const float* Wv = (const float*)d_in[3];
    float* out = (float*)d_out;

    const size_t nX = (size_t)B * T * D;
    u16* Xb = (u16*)d_ws;                          // [B*T, D] bf16
    u16* Wt = Xb + nX;                             // 3 x [D, D] bf16 transposed
    u16* Q  = Wt + 3 * (size_t)D * D;              // [B*T, D]  (Q,K,V contiguous)
    u16* Kb = Q + nX;
    u16* Vb = Kb + nX;
    u16* Vt = Vb + nX;                             // [B][D][T]
    char* rest = (char*)(Vt + nX);
    const size_t fixed   = (size_t)((char*)rest - (char*)d_ws);
    const size_t perb_E  = (size_t)T * T * 2;
    const size_t perb_rs = (size_t)T * 4;
    const bool full = ws_size >= fixed + (size_t)B * (perb_E + perb_rs);
    const int nb = full ? B : 1;
    u16*   E  = (u16*)rest;
    float* RS = (float*)(E + nb * (size_t)T * T);

    const float kfac = 1.4426950408889634f / 32.0f;  // log2(e)/sqrt(d_out)
    const int nTri128 = 136;  // sum_{bm=0..15} (bm+1), 128x128 tri tiles
    const int nCX = (int)(nX / (8 * 256));           // 4096 cast blocks
    const int nW  = 3 * (D / 32) * (D / 32);         // 3072 W-transpose blocks
    const int nRS = (nb * T) / (4 * 256);            // RS-zero blocks (float4)

    // k_qkv2 uses 144 KB dynamic LDS (3 x 48 KB buffers); opt in explicitly.
    static bool attr_done = false;
    if (!attr_done) {
        (void)hipFuncSetAttribute((const void*)k_qkv2,
                                  hipFuncAttributeMaxDynamicSharedMemorySize,
                                  147456);
        attr_done = true;
    }

    if (full) {
        // 1. prep: x-cast + W-transpose-cast + RS zero, one dispatch
        k_prep<<<dim3(nCX + nW + nRS), 256, 0, stream>>>(
            x, Wq, Wk, Wv, Xb, Wt, RS, D, nCX, nW);
        // 2. merged QKV projection, counted-vmcnt triple-buffer (T4)
        k_qkv2<<<dim3(3 * D / 256, (B * T) / 128), 512, 147456, stream>>>(
            Xb, Wt, Q, B * T, 3 * D, D);
        // 3. S (136 tri blocks/batch) + V-transpose (2048 tail-fill blocks)
        k_score_vt<<<dim3(nTri128 + (D / 32) * (T / 32), 1, B), 256, 0, stream>>>(
            Q, Kb, E, RS, Vb, Vt, T, D, kfac, nTri128);
        // 4. PV, heavy-first
        k_pv<<<dim3(D / 128, T / 128, B), 256, 0, stream>>>(E, Vt, out, RS, T, D);
    } else {
        k_prep<<<dim3(nCX + nW + nRS), 256, 0, stream>>>(
            x, Wq, Wk, Wv, Xb, Wt, RS, D, nCX, nW);
        k_qkv2<<<dim3(3 * D / 256, (B * T) / 128), 512, 147456, stream>>>(
            Xb, Wt, Q, B * T, 3 * D, D);
        for (int b = 0; b < B; ++b) {
            const size_t ob = (size_t)b * T * D;
            if (b) hipMemsetAsync(RS, 0, (size_t)T * 4, stream);
            k_score_vt<<<dim3(nTri128 + (D / 32) * (T / 32), 1, 1), 256, 0, stream>>>(
                Q + ob, Kb + ob, E, RS, Vb + ob, Vt, T, D, kfac, nTri128);
            k_pv<<<dim3(D / 128, T / 128, 1), 256, 0, stream>>>(
                E, Vt, out + ob, RS, T, D);
        }
    }
}